// Round 3
// baseline (182.494 us; speedup 1.0000x reference)
//
#include <hip/hip_runtime.h>
#include <hip/hip_bf16.h>

#define NB 4
#define NQ 512
#define NK 2048
#define ND 256
#define NH 64
#define QT 8                      // queries per attn block
#define KHALF 1024                // keys per attn block (K split in 2)

#define SCALE_C 2.8853900817779268f   // 2*log2(e): exp2(C*(q+k)) = e^{2(q+k)}
#define L2E     1.4426950408889634f

__device__ __forceinline__ float wred_sum(float v) {
#pragma unroll
    for (int off = 32; off; off >>= 1) v += __shfl_xor(v, off, 64);
    return v;
}

// ---------- kernel A: projections, pre-scaled by 2*log2(e) ----------
__global__ __launch_bounds__(256) void proj_kernel(
    const float* __restrict__ queries, const float* __restrict__ keys,
    const float* __restrict__ Wq, const float* __restrict__ Wk,
    float* __restrict__ qp, float* __restrict__ kp)
{
    __shared__ __align__(16) float in_lds[16][256];
    const int t = threadIdx.x;
    const int row0 = blockIdx.x * 16;
    const bool isQ = row0 < NB * NQ;
    const float* src = isQ ? (queries + (size_t)row0 * ND)
                           : (keys + (size_t)(row0 - NB * NQ) * ND);
    const float* W = isQ ? Wq : Wk;
    float* dst = isQ ? (qp + (size_t)row0 * NH)
                     : (kp + (size_t)(row0 - NB * NQ) * NH);

    const float4* src4 = (const float4*)src;
#pragma unroll
    for (int i = 0; i < 4; ++i) {
        int f4 = t + 256 * i;
        ((float4*)&in_lds[0][0])[f4] = src4[f4];
    }
    __syncthreads();

    const int w = t >> 6, h = t & 63;
    const int r0 = w * 4;
    float a0 = 0.f, a1 = 0.f, a2 = 0.f, a3 = 0.f;
#pragma unroll 4
    for (int d4 = 0; d4 < 64; ++d4) {
        float4 x0 = ((const float4*)in_lds[r0 + 0])[d4];
        float4 x1 = ((const float4*)in_lds[r0 + 1])[d4];
        float4 x2 = ((const float4*)in_lds[r0 + 2])[d4];
        float4 x3 = ((const float4*)in_lds[r0 + 3])[d4];
        const float* Wp = W + (size_t)(d4 * 4) * NH + h;
        float w0 = Wp[0], w1 = Wp[NH], w2 = Wp[2 * NH], w3 = Wp[3 * NH];
        a0 = fmaf(x0.x, w0, fmaf(x0.y, w1, fmaf(x0.z, w2, fmaf(x0.w, w3, a0))));
        a1 = fmaf(x1.x, w0, fmaf(x1.y, w1, fmaf(x1.z, w2, fmaf(x1.w, w3, a1))));
        a2 = fmaf(x2.x, w0, fmaf(x2.y, w1, fmaf(x2.z, w2, fmaf(x2.w, w3, a2))));
        a3 = fmaf(x3.x, w0, fmaf(x3.y, w1, fmaf(x3.z, w2, fmaf(x3.w, w3, a3))));
    }
    dst[(size_t)(r0 + 0) * NH + h] = a0 * SCALE_C;
    dst[(size_t)(r0 + 1) * NH + h] = a1 * SCALE_C;
    dst[(size_t)(r0 + 2) * NH + h] = a2 * SCALE_C;
    dst[(size_t)(r0 + 3) * NH + h] = a3 * SCALE_C;
}

// ---------- kernel B: partial scores + no-max softmax + partial PV ----------
// grid = NB * (NQ/QT) * 2 = 512 blocks, 512 threads (8 waves)
// blockIdx = (b*64 + qtile)*2 + khalf
// Scores bounded by sum|wv| (~2.5) so exp(s) never overflows: no max pass.
// Partial outputs: po[row2][d] = sum_k e_k * v_k over this K-half (unnormalized),
//                  pml[row2]  = sum_k e_k.  row2 = (b*NQ+q)*2 + khalf.
__global__ __launch_bounds__(512, 4) void attn_part(
    const float* __restrict__ values, const int* __restrict__ valid_lens,
    const float* __restrict__ wv,
    const float* __restrict__ qp, const float* __restrict__ kp,
    float* __restrict__ po, float* __restrict__ pml)
{
    __shared__ __align__(16) float qp_l[QT][NH];          // 2 KB
    __shared__ __align__(16) float wv2_l[NH];             // -2*wv
    __shared__ float sumwv_l;
    __shared__ __align__(16) float p_l[QT][KHALF];        // 32 KB e-values
    __shared__ float red_l[QT][8];

    const int t = threadIdx.x;
    const int khalf = blockIdx.x & 1;
    const int qt = (blockIdx.x >> 1) & 63;
    const int b  = blockIdx.x >> 7;
    const int q0 = qt * QT;
    const int kh0 = khalf * KHALF;

    if (t < 128) {
        int q = t >> 4, h4 = t & 15;
        ((float4*)qp_l[q])[h4] =
            ((const float4*)(qp + (size_t)(b * NQ + q0 + q) * NH))[h4];
    }
    if (t < 64) {
        float wvv = wv[t];
        wv2_l[t] = -2.0f * wvv;
        float s = wred_sum(wvv);
        if (t == 0) sumwv_l = s;
    }
    int vl = valid_lens[b];
    const int kv = vl < 0 ? 0 : (vl > NK ? NK : vl);
    const int kveff = (kv == 0) ? NK : kv;   // kv==0 -> uniform over all keys
    __syncthreads();
    const float sumwv = sumwv_l;

    // ---- phase 1: e-values into p_l, accumulate row sums ----
    float sum_q[QT];
#pragma unroll
    for (int q = 0; q < QT; ++q) sum_q[q] = 0.f;

#pragma unroll
    for (int chunk = 0; chunk < 2; ++chunk) {
        const int kl = chunk * 512 + t;      // 0..1023 local key
        const int kg = kh0 + kl;             // global key
        float e[QT];
        if (kv == 0) {
#pragma unroll
            for (int q = 0; q < QT; ++q) e[q] = 1.0f;
        } else if (kg < kv) {
            // prefetch whole kp row into registers (16 loads in flight)
            float4 kr[16];
            const float4* kpr = (const float4*)(kp + ((size_t)b * NK + kg) * NH);
#pragma unroll
            for (int i = 0; i < 16; ++i) kr[i] = kpr[i];
            float s[QT];
#pragma unroll
            for (int q = 0; q < QT; ++q) s[q] = sumwv;
#pragma unroll
            for (int h4 = 0; h4 < 16; ++h4) {
                float4 w4 = ((const float4*)wv2_l)[h4];
                float4 kh = kr[h4];
#pragma unroll
                for (int q = 0; q < QT; ++q) {
                    float4 qh = ((const float4*)qp_l[q])[h4];   // LDS broadcast
                    float r0 = __builtin_amdgcn_rcpf(__builtin_amdgcn_exp2f(qh.x + kh.x) + 1.0f);
                    float r1 = __builtin_amdgcn_rcpf(__builtin_amdgcn_exp2f(qh.y + kh.y) + 1.0f);
                    float r2 = __builtin_amdgcn_rcpf(__builtin_amdgcn_exp2f(qh.z + kh.z) + 1.0f);
                    float r3 = __builtin_amdgcn_rcpf(__builtin_amdgcn_exp2f(qh.w + kh.w) + 1.0f);
                    s[q] = fmaf(w4.x, r0, s[q]);
                    s[q] = fmaf(w4.y, r1, s[q]);
                    s[q] = fmaf(w4.z, r2, s[q]);
                    s[q] = fmaf(w4.w, r3, s[q]);
                }
            }
#pragma unroll
            for (int q = 0; q < QT; ++q) e[q] = __builtin_amdgcn_exp2f(s[q] * L2E);
        } else {
#pragma unroll
            for (int q = 0; q < QT; ++q) e[q] = 0.f;
        }
#pragma unroll
        for (int q = 0; q < QT; ++q) { p_l[q][kl] = e[q]; sum_q[q] += e[q]; }
    }
    const int wid = t >> 6;
#pragma unroll
    for (int q = 0; q < QT; ++q) {
        float s = wred_sum(sum_q[q]);
        if ((t & 63) == 0) red_l[q][wid] = s;
    }
    __syncthreads();

    // ---- phase 2: partial PV. wave w owns q=w, lanes cover d ----
    const int q = wid;
    const int dl = (t & 63) * 4;
    float l = 0.f;
#pragma unroll
    for (int i = 0; i < 8; ++i) l += red_l[q][i];

    int klend = kveff - kh0;
    klend = klend < 0 ? 0 : (klend > KHALF ? KHALF : klend);
    klend = (klend + 7) & ~7;                // tail e's are 0, safe

    float4 acc = make_float4(0.f, 0.f, 0.f, 0.f);
    const float* Vb = values + ((size_t)b * NK + kh0) * ND;
#pragma unroll 1
    for (int kk = 0; kk < klend; kk += 8) {
        float4 pa = *(const float4*)&p_l[q][kk];          // wave-uniform broadcast
        float4 pb = *(const float4*)&p_l[q][kk + 4];
        float pr[8] = {pa.x, pa.y, pa.z, pa.w, pb.x, pb.y, pb.z, pb.w};
        const float* vr = Vb + (size_t)kk * ND + dl;
#pragma unroll
        for (int j = 0; j < 8; ++j) {
            float4 v = *(const float4*)(vr + (size_t)j * ND);  // coalesced
            acc.x = fmaf(pr[j], v.x, acc.x);
            acc.y = fmaf(pr[j], v.y, acc.y);
            acc.z = fmaf(pr[j], v.z, acc.z);
            acc.w = fmaf(pr[j], v.w, acc.w);
        }
    }
    const size_t row2 = ((size_t)(b * NQ + q0 + q) * 2 + khalf);
    *(float4*)(po + row2 * ND + dl) = acc;
    if ((t & 63) == 0) pml[row2] = l;
}

// ---------- kernel C: combine the two K-halves ----------
// grid = NB*NQ/4 blocks, 256 threads; wave w handles row = blockIdx*4+w
__global__ __launch_bounds__(256) void combine_kernel(
    const float* __restrict__ po, const float* __restrict__ pml,
    float* __restrict__ out)
{
    const int t = threadIdx.x;
    const int row = blockIdx.x * 4 + (t >> 6);
    const int dl = (t & 63) * 4;
    const float l = pml[row * 2] + pml[row * 2 + 1];
    float4 o0 = *(const float4*)(po + ((size_t)row * 2) * ND + dl);
    float4 o1 = *(const float4*)(po + ((size_t)row * 2 + 1) * ND + dl);
    const float inv = 1.0f / l;
    float4 o = make_float4((o0.x + o1.x) * inv, (o0.y + o1.y) * inv,
                           (o0.z + o1.z) * inv, (o0.w + o1.w) * inv);
    *(float4*)(out + (size_t)row * ND + dl) = o;
}

extern "C" void kernel_launch(void* const* d_in, const int* in_sizes, int n_in,
                              void* d_out, int out_size, void* d_ws, size_t ws_size,
                              hipStream_t stream) {
    const float* queries   = (const float*)d_in[0];
    const float* keys      = (const float*)d_in[1];
    const float* values    = (const float*)d_in[2];
    const int* valid_lens  = (const int*)d_in[3];
    const float* Wq        = (const float*)d_in[4];
    const float* Wk        = (const float*)d_in[5];
    const float* wv        = (const float*)d_in[6];
    float* out = (float*)d_out;

    float* qp  = (float*)d_ws;                          // NB*NQ*NH
    float* kp  = qp + (size_t)NB * NQ * NH;             // NB*NK*NH
    float* po  = kp + (size_t)NB * NK * NH;             // NB*NQ*2*ND (4 MB)
    float* pml = po + (size_t)NB * NQ * 2 * ND;         // NB*NQ*2

    proj_kernel<<<(NB * NQ + NB * NK) / 16, 256, 0, stream>>>(queries, keys, Wq, Wk, qp, kp);
    attn_part<<<NB * (NQ / QT) * 2, 512, 0, stream>>>(values, valid_lens, wv, qp, kp, po, pml);
    combine_kernel<<<NB * NQ / 4, 256, 0, stream>>>(po, pml, out);
}

// Round 4
// 100.182 us; speedup vs baseline: 1.8216x; 1.8216x over previous
//
#include <hip/hip_runtime.h>
#include <hip/hip_bf16.h>

#define NB 4
#define NQ 512
#define NK 2048
#define ND 256
#define NH 64
#define QT 8                      // queries per attn block
#define KHALF 1024                // keys per attn block (K split in 2)

#define SCALE_C 2.8853900817779268f   // 2*log2(e): exp2(C*(q+k)) = e^{2(q+k)}
#define L2E     1.4426950408889634f

__device__ __forceinline__ float wred_sum(float v) {
#pragma unroll
    for (int off = 32; off; off >>= 1) v += __shfl_xor(v, off, 64);
    return v;
}

// ---------- kernel A: projections, pre-scaled by 2*log2(e) ----------
__global__ __launch_bounds__(256) void proj_kernel(
    const float* __restrict__ queries, const float* __restrict__ keys,
    const float* __restrict__ Wq, const float* __restrict__ Wk,
    float* __restrict__ qp, float* __restrict__ kp)
{
    __shared__ __align__(16) float in_lds[16][256];
    const int t = threadIdx.x;
    const int row0 = blockIdx.x * 16;
    const bool isQ = row0 < NB * NQ;
    const float* src = isQ ? (queries + (size_t)row0 * ND)
                           : (keys + (size_t)(row0 - NB * NQ) * ND);
    const float* W = isQ ? Wq : Wk;
    float* dst = isQ ? (qp + (size_t)row0 * NH)
                     : (kp + (size_t)(row0 - NB * NQ) * NH);

    const float4* src4 = (const float4*)src;
#pragma unroll
    for (int i = 0; i < 4; ++i) {
        int f4 = t + 256 * i;
        ((float4*)&in_lds[0][0])[f4] = src4[f4];
    }
    __syncthreads();

    const int w = t >> 6, h = t & 63;
    const int r0 = w * 4;
    float a0 = 0.f, a1 = 0.f, a2 = 0.f, a3 = 0.f;
#pragma unroll 4
    for (int d4 = 0; d4 < 64; ++d4) {
        float4 x0 = ((const float4*)in_lds[r0 + 0])[d4];
        float4 x1 = ((const float4*)in_lds[r0 + 1])[d4];
        float4 x2 = ((const float4*)in_lds[r0 + 2])[d4];
        float4 x3 = ((const float4*)in_lds[r0 + 3])[d4];
        const float* Wp = W + (size_t)(d4 * 4) * NH + h;
        float w0 = Wp[0], w1 = Wp[NH], w2 = Wp[2 * NH], w3 = Wp[3 * NH];
        a0 = fmaf(x0.x, w0, fmaf(x0.y, w1, fmaf(x0.z, w2, fmaf(x0.w, w3, a0))));
        a1 = fmaf(x1.x, w0, fmaf(x1.y, w1, fmaf(x1.z, w2, fmaf(x1.w, w3, a1))));
        a2 = fmaf(x2.x, w0, fmaf(x2.y, w1, fmaf(x2.z, w2, fmaf(x2.w, w3, a2))));
        a3 = fmaf(x3.x, w0, fmaf(x3.y, w1, fmaf(x3.z, w2, fmaf(x3.w, w3, a3))));
    }
    dst[(size_t)(r0 + 0) * NH + h] = a0 * SCALE_C;
    dst[(size_t)(r0 + 1) * NH + h] = a1 * SCALE_C;
    dst[(size_t)(r0 + 2) * NH + h] = a2 * SCALE_C;
    dst[(size_t)(r0 + 3) * NH + h] = a3 * SCALE_C;
}

// ---------- kernel B: partial scores + no-max softmax + partial PV ----------
// grid = NB*(NQ/QT)*2 = 512 blocks, 512 threads (8 waves)
// blockIdx = (b*64 + qtile)*2 + khalf
// PV: waves split the K range (wave w takes rows k = w mod 8), each wave keeps
// acc[8 q] so every V element feeds 8 FMAs (V read ONCE per block).
// Cross-wave tree-reduction reuses p_lt's 32 KB as scratch.
__global__ __launch_bounds__(512, 4) void attn_part(
    const float* __restrict__ values, const int* __restrict__ valid_lens,
    const float* __restrict__ wv,
    const float* __restrict__ qp, const float* __restrict__ kp,
    float* __restrict__ po, float* __restrict__ pml)
{
    __shared__ __align__(16) float qp_l[QT][NH];          // 2 KB
    __shared__ __align__(16) float wv2_l[NH];             // -2*wv
    __shared__ float sumwv_l;
    __shared__ __align__(16) float p_lt[KHALF][QT];       // 32 KB, k-major e-values
    __shared__ float red_l[QT][8];

    const int t = threadIdx.x;
    const int khalf = blockIdx.x & 1;
    const int qt = (blockIdx.x >> 1) & 63;
    const int b  = blockIdx.x >> 7;
    const int q0 = qt * QT;
    const int kh0 = khalf * KHALF;
    const int wid = t >> 6;
    const int dl = (t & 63) * 4;

    if (t < 128) {
        int q = t >> 4, h4 = t & 15;
        ((float4*)qp_l[q])[h4] =
            ((const float4*)(qp + (size_t)(b * NQ + q0 + q) * NH))[h4];
    }
    if (t < 64) {
        float wvv = wv[t];
        wv2_l[t] = -2.0f * wvv;
        float s = wred_sum(wvv);
        if (t == 0) sumwv_l = s;
    }
    int vl = valid_lens[b];
    const int kv = vl < 0 ? 0 : (vl > NK ? NK : vl);
    const int kveff = (kv == 0) ? NK : kv;   // kv==0 -> uniform over all keys
    __syncthreads();
    const float sumwv = sumwv_l;

    // ---- phase 1: e-values into p_lt (k-major), accumulate row sums ----
    float sum_q[QT];
#pragma unroll
    for (int q = 0; q < QT; ++q) sum_q[q] = 0.f;

#pragma unroll
    for (int chunk = 0; chunk < 2; ++chunk) {
        const int kl = chunk * 512 + t;      // 0..1023 local key
        const int kg = kh0 + kl;             // global key
        float e[QT];
        if (kv == 0) {
#pragma unroll
            for (int q = 0; q < QT; ++q) e[q] = 1.0f;
        } else if (kg < kv) {
            float s[QT];
#pragma unroll
            for (int q = 0; q < QT; ++q) s[q] = sumwv;
            const float4* kpr = (const float4*)(kp + ((size_t)b * NK + kg) * NH);
#pragma unroll
            for (int half = 0; half < 2; ++half) {
                float4 kr[8];                // 8 loads in flight per half
#pragma unroll
                for (int i = 0; i < 8; ++i) kr[i] = kpr[half * 8 + i];
#pragma unroll
                for (int i = 0; i < 8; ++i) {
                    const int h4 = half * 8 + i;
                    float4 w4 = ((const float4*)wv2_l)[h4];
                    float4 kh = kr[i];
#pragma unroll
                    for (int q = 0; q < QT; ++q) {
                        float4 qh = ((const float4*)qp_l[q])[h4];   // LDS broadcast
                        float r0 = __builtin_amdgcn_rcpf(__builtin_amdgcn_exp2f(qh.x + kh.x) + 1.0f);
                        float r1 = __builtin_amdgcn_rcpf(__builtin_amdgcn_exp2f(qh.y + kh.y) + 1.0f);
                        float r2 = __builtin_amdgcn_rcpf(__builtin_amdgcn_exp2f(qh.z + kh.z) + 1.0f);
                        float r3 = __builtin_amdgcn_rcpf(__builtin_amdgcn_exp2f(qh.w + kh.w) + 1.0f);
                        s[q] = fmaf(w4.x, r0, s[q]);
                        s[q] = fmaf(w4.y, r1, s[q]);
                        s[q] = fmaf(w4.z, r2, s[q]);
                        s[q] = fmaf(w4.w, r3, s[q]);
                    }
                }
            }
#pragma unroll
            for (int q = 0; q < QT; ++q) e[q] = __builtin_amdgcn_exp2f(s[q] * L2E);
        } else {
#pragma unroll
            for (int q = 0; q < QT; ++q) e[q] = 0.f;
        }
        *(float4*)&p_lt[kl][0] = make_float4(e[0], e[1], e[2], e[3]);
        *(float4*)&p_lt[kl][4] = make_float4(e[4], e[5], e[6], e[7]);
#pragma unroll
        for (int q = 0; q < QT; ++q) sum_q[q] += e[q];
    }
#pragma unroll
    for (int q = 0; q < QT; ++q) {
        float s = wred_sum(sum_q[q]);
        if ((t & 63) == 0) red_l[q][wid] = s;
    }
    __syncthreads();

    // ---- phase 2: PV, waves split k (row k handled by wave k%8) ----
    int klend = kveff - kh0;
    klend = klend < 0 ? 0 : (klend > KHALF ? KHALF : klend);
    const int klend32 = (klend + 31) & ~31;  // tail rows have e=0; uniform trips

    float4 acc[QT];
#pragma unroll
    for (int q = 0; q < QT; ++q) acc[q] = make_float4(0.f, 0.f, 0.f, 0.f);

    const float* Vb = values + ((size_t)b * NK + kh0) * ND;
#pragma unroll 4
    for (int kl = wid; kl < klend32; kl += 8) {
        float4 pA = *(const float4*)&p_lt[kl][0];   // wave-uniform broadcast
        float4 pB = *(const float4*)&p_lt[kl][4];
        float4 v = *(const float4*)(Vb + (size_t)kl * ND + dl);  // coalesced 1KB
        acc[0].x = fmaf(pA.x, v.x, acc[0].x); acc[0].y = fmaf(pA.x, v.y, acc[0].y);
        acc[0].z = fmaf(pA.x, v.z, acc[0].z); acc[0].w = fmaf(pA.x, v.w, acc[0].w);
        acc[1].x = fmaf(pA.y, v.x, acc[1].x); acc[1].y = fmaf(pA.y, v.y, acc[1].y);
        acc[1].z = fmaf(pA.y, v.z, acc[1].z); acc[1].w = fmaf(pA.y, v.w, acc[1].w);
        acc[2].x = fmaf(pA.z, v.x, acc[2].x); acc[2].y = fmaf(pA.z, v.y, acc[2].y);
        acc[2].z = fmaf(pA.z, v.z, acc[2].z); acc[2].w = fmaf(pA.z, v.w, acc[2].w);
        acc[3].x = fmaf(pA.w, v.x, acc[3].x); acc[3].y = fmaf(pA.w, v.y, acc[3].y);
        acc[3].z = fmaf(pA.w, v.z, acc[3].z); acc[3].w = fmaf(pA.w, v.w, acc[3].w);
        acc[4].x = fmaf(pB.x, v.x, acc[4].x); acc[4].y = fmaf(pB.x, v.y, acc[4].y);
        acc[4].z = fmaf(pB.x, v.z, acc[4].z); acc[4].w = fmaf(pB.x, v.w, acc[4].w);
        acc[5].x = fmaf(pB.y, v.x, acc[5].x); acc[5].y = fmaf(pB.y, v.y, acc[5].y);
        acc[5].z = fmaf(pB.y, v.z, acc[5].z); acc[5].w = fmaf(pB.y, v.w, acc[5].w);
        acc[6].x = fmaf(pB.z, v.x, acc[6].x); acc[6].y = fmaf(pB.z, v.y, acc[6].y);
        acc[6].z = fmaf(pB.z, v.z, acc[6].z); acc[6].w = fmaf(pB.z, v.w, acc[6].w);
        acc[7].x = fmaf(pB.w, v.x, acc[7].x); acc[7].y = fmaf(pB.w, v.y, acc[7].y);
        acc[7].z = fmaf(pB.w, v.z, acc[7].z); acc[7].w = fmaf(pB.w, v.w, acc[7].w);
    }
    __syncthreads();                          // p_lt now dead -> reuse as scratch

    // ---- phase 3: tree-reduce partials across waves (8 -> 4 -> 2 -> 1) ----
    float* red = (float*)&p_lt[0][0];         // 4 slots x 8 KB (2048 floats)
    if (wid >= 4) {
        float* s = red + (size_t)(wid - 4) * 2048;
#pragma unroll
        for (int q = 0; q < QT; ++q) *(float4*)(s + q * 256 + dl) = acc[q];
    }
    __syncthreads();
    if (wid < 4) {
        const float* s = red + (size_t)wid * 2048;
#pragma unroll
        for (int q = 0; q < QT; ++q) {
            float4 r = *(const float4*)(s + q * 256 + dl);
            acc[q].x += r.x; acc[q].y += r.y; acc[q].z += r.z; acc[q].w += r.w;
        }
    }
    __syncthreads();
    if (wid >= 2 && wid < 4) {
        float* s = red + (size_t)(wid - 2) * 2048;
#pragma unroll
        for (int q = 0; q < QT; ++q) *(float4*)(s + q * 256 + dl) = acc[q];
    }
    __syncthreads();
    if (wid < 2) {
        const float* s = red + (size_t)wid * 2048;
#pragma unroll
        for (int q = 0; q < QT; ++q) {
            float4 r = *(const float4*)(s + q * 256 + dl);
            acc[q].x += r.x; acc[q].y += r.y; acc[q].z += r.z; acc[q].w += r.w;
        }
    }
    __syncthreads();
    if (wid == 1) {
#pragma unroll
        for (int q = 0; q < QT; ++q) *(float4*)(red + q * 256 + dl) = acc[q];
    }
    __syncthreads();
    if (wid == 0) {
#pragma unroll
        for (int q = 0; q < QT; ++q) {
            float4 r = *(const float4*)(red + q * 256 + dl);
            acc[q].x += r.x; acc[q].y += r.y; acc[q].z += r.z; acc[q].w += r.w;
            const size_t row2 = ((size_t)(b * NQ + q0 + q) * 2 + khalf);
            *(float4*)(po + row2 * ND + dl) = acc[q];
        }
        if (t < QT) {
            float l = 0.f;
#pragma unroll
            for (int i = 0; i < 8; ++i) l += red_l[t][i];
            pml[((size_t)(b * NQ + q0 + t) * 2 + khalf)] = l;
        }
    }
}

// ---------- kernel C: combine the two K-halves ----------
__global__ __launch_bounds__(256) void combine_kernel(
    const float* __restrict__ po, const float* __restrict__ pml,
    float* __restrict__ out)
{
    const int t = threadIdx.x;
    const int row = blockIdx.x * 4 + (t >> 6);
    const int dl = (t & 63) * 4;
    const float l = pml[row * 2] + pml[row * 2 + 1];
    float4 o0 = *(const float4*)(po + ((size_t)row * 2) * ND + dl);
    float4 o1 = *(const float4*)(po + ((size_t)row * 2 + 1) * ND + dl);
    const float inv = 1.0f / l;
    float4 o = make_float4((o0.x + o1.x) * inv, (o0.y + o1.y) * inv,
                           (o0.z + o1.z) * inv, (o0.w + o1.w) * inv);
    *(float4*)(out + (size_t)row * ND + dl) = o;
}

extern "C" void kernel_launch(void* const* d_in, const int* in_sizes, int n_in,
                              void* d_out, int out_size, void* d_ws, size_t ws_size,
                              hipStream_t stream) {
    const float* queries   = (const float*)d_in[0];
    const float* keys      = (const float*)d_in[1];
    const float* values    = (const float*)d_in[2];
    const int* valid_lens  = (const int*)d_in[3];
    const float* Wq        = (const float*)d_in[4];
    const float* Wk        = (const float*)d_in[5];
    const float* wv        = (const float*)d_in[6];
    float* out = (float*)d_out;

    float* qp  = (float*)d_ws;                          // NB*NQ*NH
    float* kp  = qp + (size_t)NB * NQ * NH;             // NB*NK*NH
    float* po  = kp + (size_t)NB * NK * NH;             // NB*NQ*2*ND
    float* pml = po + (size_t)NB * NQ * 2 * ND;         // NB*NQ*2

    proj_kernel<<<(NB * NQ + NB * NK) / 16, 256, 0, stream>>>(queries, keys, Wq, Wk, qp, kp);
    attn_part<<<NB * (NQ / QT) * 2, 512, 0, stream>>>(values, valid_lens, wv, qp, kp, po, pml);
    combine_kernel<<<NB * NQ / 4, 256, 0, stream>>>(po, pml, out);
}

// Round 5
// 84.881 us; speedup vs baseline: 2.1500x; 1.1803x over previous
//
#include <hip/hip_runtime.h>
#include <hip/hip_bf16.h>

#define NB 4
#define NQ 512
#define NK 2048
#define ND 256
#define NH 64
#define QT 8                      // queries per attn block
#define KQ 512                    // keys per attn block (K split in 4)
#define KSPLIT 4

#define SCALE_C 2.8853900817779268f   // 2*log2(e): exp2(C*(q+k)) = e^{2(q+k)}
#define L2E     1.4426950408889634f

__device__ __forceinline__ float wred_sum(float v) {
#pragma unroll
    for (int off = 32; off; off >>= 1) v += __shfl_xor(v, off, 64);
    return v;
}

// ---------- kernel A: projections, pre-scaled by 2*log2(e) ----------
// queries -> qp[b*NQ+q][h] (row-major); keys -> kpT[b][h][k] (TRANSPOSED)
__global__ __launch_bounds__(256) void proj_kernel(
    const float* __restrict__ queries, const float* __restrict__ keys,
    const float* __restrict__ Wq, const float* __restrict__ Wk,
    float* __restrict__ qp, float* __restrict__ kpT)
{
    __shared__ __align__(16) float in_lds[16][256];
    const int t = threadIdx.x;
    const int row0 = blockIdx.x * 16;
    const bool isQ = row0 < NB * NQ;
    const float* src = isQ ? (queries + (size_t)row0 * ND)
                           : (keys + (size_t)(row0 - NB * NQ) * ND);
    const float* W = isQ ? Wq : Wk;

    const float4* src4 = (const float4*)src;
#pragma unroll
    for (int i = 0; i < 4; ++i) {
        int f4 = t + 256 * i;
        ((float4*)&in_lds[0][0])[f4] = src4[f4];
    }
    __syncthreads();

    const int w = t >> 6, h = t & 63;
    const int r0 = w * 4;
    float a[4] = {0.f, 0.f, 0.f, 0.f};
#pragma unroll 4
    for (int d4 = 0; d4 < 64; ++d4) {
        const float* Wp = W + (size_t)(d4 * 4) * NH + h;
        float w0 = Wp[0], w1 = Wp[NH], w2 = Wp[2 * NH], w3 = Wp[3 * NH];
#pragma unroll
        for (int i = 0; i < 4; ++i) {
            float4 x = ((const float4*)in_lds[r0 + i])[d4];
            a[i] = fmaf(x.x, w0, fmaf(x.y, w1, fmaf(x.z, w2, fmaf(x.w, w3, a[i]))));
        }
    }
    if (isQ) {
#pragma unroll
        for (int i = 0; i < 4; ++i)
            qp[(size_t)(row0 + r0 + i) * NH + h] = a[i] * SCALE_C;
    } else {
#pragma unroll
        for (int i = 0; i < 4; ++i) {
            int kr = row0 - NB * NQ + r0 + i;         // global key row
            int b = kr >> 11, k = kr & (NK - 1);
            kpT[((size_t)((b << 6) + h)) * NK + k] = a[i] * SCALE_C;  // scattered, tiny
        }
    }
}

// ---------- kernel B: partial scores + no-max softmax + partial PV ----------
// grid = NB*(NQ/QT)*KSPLIT = 1024 blocks, 512 threads (8 waves), all resident.
// Block decode (diagonal batch<->kq pairing for load balance):
//   g = n & 255, kq = n >> 8, b = ((g>>6)+kq)&3, qt = g&63.
// Scores bounded by ~2*sum|wv| so exp(s) never overflows: no max pass.
__global__ __launch_bounds__(512, 8) void attn_part(
    const float* __restrict__ values, const int* __restrict__ valid_lens,
    const float* __restrict__ wv,
    const float* __restrict__ qp, const float* __restrict__ kpT,
    float* __restrict__ po, float* __restrict__ pml)
{
    __shared__ __align__(16) float qp_l[QT][NH];      // 2 KB
    __shared__ __align__(16) float wv2_l[NH];         // -2*wv
    __shared__ float sumwv_l;
    __shared__ __align__(16) float buf[8192];         // 32 KB: p (k-major, 16KB) / red scratch
    __shared__ float red_l[QT][8];

    const int t = threadIdx.x;
    const int n = blockIdx.x;
    const int g = n & 255;
    const int kq = n >> 8;
    const int b  = ((g >> 6) + kq) & 3;
    const int qt = g & 63;
    const int q0 = qt * QT;
    const int kh0 = kq * KQ;
    const int wid = t >> 6;
    const int dl = (t & 63) * 4;

    if (t < 128) {
        int q = t >> 4, h4 = t & 15;
        ((float4*)qp_l[q])[h4] =
            ((const float4*)(qp + (size_t)(b * NQ + q0 + q) * NH))[h4];
    }
    if (t < 64) {
        float wvv = wv[t];
        wv2_l[t] = -2.0f * wvv;
        float s = wred_sum(wvv);
        if (t == 0) sumwv_l = s;
    }
    int vl = valid_lens[b];
    const int kv = vl < 0 ? 0 : (vl > NK ? NK : vl);
    const int kveff = (kv == 0) ? NK : kv;   // kv==0 -> uniform over all keys
    __syncthreads();
    const float sumwv = sumwv_l;

    // ---- phase 1: e-values into buf (k-major [KQ][8]), one k per thread ----
    const int kg = kh0 + t;                  // this thread's global key
    float e[QT];
    if (kv == 0) {
#pragma unroll
        for (int q = 0; q < QT; ++q) e[q] = 1.0f;
    } else if (kg < kv) {
        float s[QT];
#pragma unroll
        for (int q = 0; q < QT; ++q) s[q] = sumwv;
        const float* kT = kpT + ((size_t)(b << 6)) * NK + kg;   // h-stride = NK, coalesced
#pragma unroll
        for (int hb = 0; hb < 8; ++hb) {
            float kh[8];
#pragma unroll
            for (int i = 0; i < 8; ++i) kh[i] = kT[(size_t)(hb * 8 + i) * NK];
#pragma unroll
            for (int hq = 0; hq < 2; ++hq) {
                const int h4 = hb * 2 + hq;
                float4 w4 = ((const float4*)wv2_l)[h4];
                float k0 = kh[hq * 4], k1 = kh[hq * 4 + 1],
                      k2 = kh[hq * 4 + 2], k3 = kh[hq * 4 + 3];
#pragma unroll
                for (int q = 0; q < QT; ++q) {
                    float4 qh = ((const float4*)qp_l[q])[h4];   // LDS broadcast
                    float r0 = __builtin_amdgcn_rcpf(__builtin_amdgcn_exp2f(qh.x + k0) + 1.0f);
                    float r1 = __builtin_amdgcn_rcpf(__builtin_amdgcn_exp2f(qh.y + k1) + 1.0f);
                    float r2 = __builtin_amdgcn_rcpf(__builtin_amdgcn_exp2f(qh.z + k2) + 1.0f);
                    float r3 = __builtin_amdgcn_rcpf(__builtin_amdgcn_exp2f(qh.w + k3) + 1.0f);
                    s[q] = fmaf(w4.x, r0, s[q]);
                    s[q] = fmaf(w4.y, r1, s[q]);
                    s[q] = fmaf(w4.z, r2, s[q]);
                    s[q] = fmaf(w4.w, r3, s[q]);
                }
            }
        }
#pragma unroll
        for (int q = 0; q < QT; ++q) e[q] = __builtin_amdgcn_exp2f(s[q] * L2E);
    } else {
#pragma unroll
        for (int q = 0; q < QT; ++q) e[q] = 0.f;
    }
    *(float4*)&buf[t * 8]     = make_float4(e[0], e[1], e[2], e[3]);
    *(float4*)&buf[t * 8 + 4] = make_float4(e[4], e[5], e[6], e[7]);
#pragma unroll
    for (int q = 0; q < QT; ++q) {
        float s = wred_sum(e[q]);
        if ((t & 63) == 0) red_l[q][wid] = s;
    }
    __syncthreads();

    // ---- phase 2: PV, waves split k (row kl handled by wave kl%8) ----
    int klend = kveff - kh0;
    klend = klend < 0 ? 0 : (klend > KQ ? KQ : klend);
    const int klend8 = (klend + 7) & ~7;     // tail rows have e=0

    float4 acc[QT];
#pragma unroll
    for (int q = 0; q < QT; ++q) acc[q] = make_float4(0.f, 0.f, 0.f, 0.f);

    const float* Vb = values + ((size_t)b * NK + kh0) * ND;
#pragma unroll 2
    for (int kl = wid; kl < klend8; kl += 8) {
        float4 pA = *(const float4*)&buf[kl * 8];       // wave-uniform broadcast
        float4 pB = *(const float4*)&buf[kl * 8 + 4];
        float4 v = *(const float4*)(Vb + (size_t)kl * ND + dl);  // coalesced 1KB
        acc[0].x = fmaf(pA.x, v.x, acc[0].x); acc[0].y = fmaf(pA.x, v.y, acc[0].y);
        acc[0].z = fmaf(pA.x, v.z, acc[0].z); acc[0].w = fmaf(pA.x, v.w, acc[0].w);
        acc[1].x = fmaf(pA.y, v.x, acc[1].x); acc[1].y = fmaf(pA.y, v.y, acc[1].y);
        acc[1].z = fmaf(pA.y, v.z, acc[1].z); acc[1].w = fmaf(pA.y, v.w, acc[1].w);
        acc[2].x = fmaf(pA.z, v.x, acc[2].x); acc[2].y = fmaf(pA.z, v.y, acc[2].y);
        acc[2].z = fmaf(pA.z, v.z, acc[2].z); acc[2].w = fmaf(pA.z, v.w, acc[2].w);
        acc[3].x = fmaf(pA.w, v.x, acc[3].x); acc[3].y = fmaf(pA.w, v.y, acc[3].y);
        acc[3].z = fmaf(pA.w, v.z, acc[3].z); acc[3].w = fmaf(pA.w, v.w, acc[3].w);
        acc[4].x = fmaf(pB.x, v.x, acc[4].x); acc[4].y = fmaf(pB.x, v.y, acc[4].y);
        acc[4].z = fmaf(pB.x, v.z, acc[4].z); acc[4].w = fmaf(pB.x, v.w, acc[4].w);
        acc[5].x = fmaf(pB.y, v.x, acc[5].x); acc[5].y = fmaf(pB.y, v.y, acc[5].y);
        acc[5].z = fmaf(pB.y, v.z, acc[5].z); acc[5].w = fmaf(pB.y, v.w, acc[5].w);
        acc[6].x = fmaf(pB.z, v.x, acc[6].x); acc[6].y = fmaf(pB.z, v.y, acc[6].y);
        acc[6].z = fmaf(pB.z, v.z, acc[6].z); acc[6].w = fmaf(pB.z, v.w, acc[6].w);
        acc[7].x = fmaf(pB.w, v.x, acc[7].x); acc[7].y = fmaf(pB.w, v.y, acc[7].y);
        acc[7].z = fmaf(pB.w, v.z, acc[7].z); acc[7].w = fmaf(pB.w, v.w, acc[7].w);
    }
    __syncthreads();                          // p-values dead -> reuse buf as scratch

    // ---- phase 3: tree-reduce partials across waves (8 -> 4 -> 2 -> 1) ----
    if (wid >= 4) {
        float* s = buf + (size_t)(wid - 4) * 2048;
#pragma unroll
        for (int q = 0; q < QT; ++q) *(float4*)(s + q * 256 + dl) = acc[q];
    }
    __syncthreads();
    if (wid < 4) {
        const float* s = buf + (size_t)wid * 2048;
#pragma unroll
        for (int q = 0; q < QT; ++q) {
            float4 r = *(const float4*)(s + q * 256 + dl);
            acc[q].x += r.x; acc[q].y += r.y; acc[q].z += r.z; acc[q].w += r.w;
        }
    }
    __syncthreads();
    if (wid >= 2 && wid < 4) {
        float* s = buf + (size_t)(wid - 2) * 2048;
#pragma unroll
        for (int q = 0; q < QT; ++q) *(float4*)(s + q * 256 + dl) = acc[q];
    }
    __syncthreads();
    if (wid < 2) {
        const float* s = buf + (size_t)wid * 2048;
#pragma unroll
        for (int q = 0; q < QT; ++q) {
            float4 r = *(const float4*)(s + q * 256 + dl);
            acc[q].x += r.x; acc[q].y += r.y; acc[q].z += r.z; acc[q].w += r.w;
        }
    }
    __syncthreads();
    if (wid == 1) {
#pragma unroll
        for (int q = 0; q < QT; ++q) *(float4*)(buf + q * 256 + dl) = acc[q];
    }
    __syncthreads();
    if (wid == 0) {
#pragma unroll
        for (int q = 0; q < QT; ++q) {
            float4 r = *(const float4*)(buf + q * 256 + dl);
            acc[q].x += r.x; acc[q].y += r.y; acc[q].z += r.z; acc[q].w += r.w;
            const size_t row4 = ((size_t)(b * NQ + q0 + q) * KSPLIT + kq);
            *(float4*)(po + row4 * ND + dl) = acc[q];
        }
        if (t < QT) {
            float l = 0.f;
#pragma unroll
            for (int i = 0; i < 8; ++i) l += red_l[t][i];
            pml[((size_t)(b * NQ + q0 + t) * KSPLIT + kq)] = l;
        }
    }
}

// ---------- kernel C: combine the four K-quarters ----------
__global__ __launch_bounds__(256) void combine_kernel(
    const float* __restrict__ po, const float* __restrict__ pml,
    float* __restrict__ out)
{
    const int t = threadIdx.x;
    const int row = blockIdx.x * 4 + (t >> 6);
    const int dl = (t & 63) * 4;
    float l = 0.f;
#pragma unroll
    for (int s = 0; s < KSPLIT; ++s) l += pml[row * KSPLIT + s];
    float4 o = make_float4(0.f, 0.f, 0.f, 0.f);
#pragma unroll
    for (int s = 0; s < KSPLIT; ++s) {
        float4 p = *(const float4*)(po + ((size_t)row * KSPLIT + s) * ND + dl);
        o.x += p.x; o.y += p.y; o.z += p.z; o.w += p.w;
    }
    const float inv = 1.0f / l;
    o.x *= inv; o.y *= inv; o.z *= inv; o.w *= inv;
    *(float4*)(out + (size_t)row * ND + dl) = o;
}

extern "C" void kernel_launch(void* const* d_in, const int* in_sizes, int n_in,
                              void* d_out, int out_size, void* d_ws, size_t ws_size,
                              hipStream_t stream) {
    const float* queries   = (const float*)d_in[0];
    const float* keys      = (const float*)d_in[1];
    const float* values    = (const float*)d_in[2];
    const int* valid_lens  = (const int*)d_in[3];
    const float* Wq        = (const float*)d_in[4];
    const float* Wk        = (const float*)d_in[5];
    const float* wv        = (const float*)d_in[6];
    float* out = (float*)d_out;

    float* qp  = (float*)d_ws;                          // NB*NQ*NH      (0.5 MB)
    float* kpT = qp + (size_t)NB * NQ * NH;             // NB*NH*NK      (2 MB)
    float* po  = kpT + (size_t)NB * NH * NK;            // NB*NQ*4*ND    (8 MB)
    float* pml = po + (size_t)NB * NQ * KSPLIT * ND;    // NB*NQ*4

    proj_kernel<<<(NB * NQ + NB * NK) / 16, 256, 0, stream>>>(queries, keys, Wq, Wk, qp, kpT);
    attn_part<<<NB * (NQ / QT) * KSPLIT, 512, 0, stream>>>(values, valid_lens, wv, qp, kpT, po, pml);
    combine_kernel<<<NB * NQ / 4, 256, 0, stream>>>(po, pml, out);
}